// Round 2
// baseline (179.705 us; speedup 1.0000x reference)
//
#include <hip/hip_runtime.h>

// SSIM, N=32 images 512x512 fp32, 11x11 Gaussian (separable), zero pad,
// scalar mean output.
//
// R2 design: barrier-free / LDS-free streaming separable conv.
// - 64-thread blocks (one wave); thread owns M=4 columns; 2 bands x 32 row
//   chunks x 32 images = 2048 independent waves (8 waves/CU at <=256 VGPR).
// - Per input row: load 14-col window straight from global (5 float4 per
//   plane, L1 absorbs the lane overlap), compute p=x^2+y^2, q=x*y once per
//   element, horizontal 11-tap conv for 4 planes via fused scatter,
// - vertical 11-tap conv from a register ring (mod-11 static via 11x unroll),
//   SSIM epilogue, wave shuffle reduce, one atomicAdd per wave.

#define IMG_H 512
#define IMG_W 512
#define NIMG  32
#define M     4                  // columns per thread
#define RROWS 16                 // output rows per block
#define ITERS (RROWS + 10)       // 26 input rows streamed
#define NB4   (IMG_W / 4)        // 128 float4 blocks per row

#define C1F  1.0e-4f
#define C2F  9.0e-4f
#define EPSF 1.0e-8f

__global__ __launch_bounds__(64, 2) void ssim_kernel(
    const float* __restrict__ xg, const float* __restrict__ yg,
    const float* __restrict__ wg, float* __restrict__ out)
{
    const int lane = threadIdx.x;          // 0..63
    const int band = blockIdx.x;           // 0..1
    const int chnk = blockIdx.y;           // 0..31
    const int img  = blockIdx.z;           // 0..31
    const int r0   = chnk * RROWS;
    const int fb0  = band * 64 + lane - 2; // first float4 block of window

    const float* xb = xg + (size_t)img * (IMG_H * IMG_W);
    const float* yb = yg + (size_t)img * (IMG_H * IMG_W);

    // 1D taps = row sums of normalized 2D window; broadcast to SGPRs.
    float rs = 0.f;
    if (lane < 11) {
        #pragma unroll
        for (int j = 0; j < 11; ++j) rs += wg[lane * 11 + j];
    }
    float g[11];
    #pragma unroll
    for (int k = 0; k < 11; ++k) {
        int gi = __shfl(__float_as_int(rs), k, 64);
        g[k] = __int_as_float(__builtin_amdgcn_readfirstlane(gi));
    }

    // vertical register rings: 4 planes x 4 cols x 11 rows
    float rx[11][M], ry[11][M], rp[11][M], rq[11][M];

    const float4 z4 = make_float4(0.f, 0.f, 0.f, 0.f);
    float acc = 0.f;

    for (int ii = 0; ii < 33; ii += 11) {
        #pragma unroll
        for (int s = 0; s < 11; ++s) {
            const int i = ii + s;
            if (i < ITERS) {
                const int r = r0 - 5 + i;             // input row (uniform)
                float4 xv[5], yv[5];
                if ((unsigned)r < IMG_H) {            // uniform branch
                    const float4* xr4 = (const float4*)(xb + (size_t)r * IMG_W);
                    const float4* yr4 = (const float4*)(yb + (size_t)r * IMG_W);
                    #pragma unroll
                    for (int k = 0; k < 5; ++k) {
                        const int fb = fb0 + k;
                        const bool ok = ((unsigned)fb < NB4);
                        xv[k] = ok ? xr4[fb] : z4;
                        yv[k] = ok ? yr4[fb] : z4;
                    }
                } else {
                    #pragma unroll
                    for (int k = 0; k < 5; ++k) { xv[k] = z4; yv[k] = z4; }
                }

                float xw[20], yw[20];
                #pragma unroll
                for (int k = 0; k < 5; ++k) {
                    xw[4*k+0] = xv[k].x; xw[4*k+1] = xv[k].y;
                    xw[4*k+2] = xv[k].z; xw[4*k+3] = xv[k].w;
                    yw[4*k+0] = yv[k].x; yw[4*k+1] = yv[k].y;
                    yw[4*k+2] = yv[k].z; yw[4*k+3] = yv[k].w;
                }

                // fused prep + horizontal conv (window cols = xw[3..16])
                float hx[M] = {0,0,0,0}, hy[M] = {0,0,0,0};
                float hp[M] = {0,0,0,0}, hq[M] = {0,0,0,0};
                #pragma unroll
                for (int e = 3; e <= 16; ++e) {
                    const float xe = xw[e], ye = yw[e];
                    const float pe = fmaf(xe, xe, ye * ye);
                    const float qe = xe * ye;
                    const int jlo = (e - 13 > 0) ? (e - 13) : 0;
                    const int jhi = (e - 3 < M - 1) ? (e - 3) : (M - 1);
                    #pragma unroll
                    for (int j = jlo; j <= jhi; ++j) {
                        const float gk = g[e - 3 - j];
                        hx[j] = fmaf(gk, xe, hx[j]);
                        hy[j] = fmaf(gk, ye, hy[j]);
                        hp[j] = fmaf(gk, pe, hp[j]);
                        hq[j] = fmaf(gk, qe, hq[j]);
                    }
                }
                #pragma unroll
                for (int j = 0; j < M; ++j) {
                    rx[s][j] = hx[j]; ry[s][j] = hy[j];
                    rp[s][j] = hp[j]; rq[s][j] = hq[j];
                }

                if (i >= 10) {                        // output row r0 + i - 10
                    #pragma unroll
                    for (int j = 0; j < M; ++j) {
                        float mx = 0.f, my = 0.f, mp = 0.f, mq = 0.f;
                        #pragma unroll
                        for (int t = 0; t < 11; ++t) {
                            const int sl = (s + 1 + t) % 11;   // static
                            mx = fmaf(g[t], rx[sl][j], mx);
                            my = fmaf(g[t], ry[sl][j], my);
                            mp = fmaf(g[t], rp[sl][j], mp);
                            mq = fmaf(g[t], rq[sl][j], mq);
                        }
                        const float mux2 = mx * mx;
                        const float muy2 = my * my;
                        const float muxy = mx * my;
                        const float a    = mux2 + muy2;
                        const float sxy  = mq - muxy;
                        const float ssum = mp - a;
                        const float num  = fmaf(2.f, muxy, C1F) * fmaf(2.f, sxy, C2F);
                        const float den  = (a + C1F) * (ssum + C2F);
                        float v = num * __builtin_amdgcn_rcpf(den + EPSF);
                        v = fminf(fmaxf(v, 0.f), 1.f);
                        acc += v;
                    }
                }
            }
        }
    }

    // wave reduction + one atomic per wave
    #pragma unroll
    for (int off = 32; off > 0; off >>= 1)
        acc += __shfl_down(acc, off, 64);
    if (lane == 0)
        atomicAdd(out, acc * (1.0f / (float)((size_t)NIMG * IMG_H * IMG_W)));
}

extern "C" void kernel_launch(void* const* d_in, const int* in_sizes, int n_in,
                              void* d_out, int out_size, void* d_ws, size_t ws_size,
                              hipStream_t stream) {
    const float* x = (const float*)d_in[0];
    const float* y = (const float*)d_in[1];
    const float* w = (const float*)d_in[2];
    float* out = (float*)d_out;

    // d_out is re-poisoned to 0xAA before every timed launch; zero it first.
    hipMemsetAsync(out, 0, sizeof(float), stream);

    dim3 grid(IMG_W / (64 * M), IMG_H / RROWS, NIMG);   // (2, 32, 32)
    ssim_kernel<<<grid, dim3(64), 0, stream>>>(x, y, w, out);
}